// Round 15
// baseline (171.489 us; speedup 1.0000x reference)
//
#include <hip/hip_runtime.h>
#include <math.h>

#define NB 8
#define NE 128
#define NS 4096
#define CSCALE 0.12751743f   // log2(e)/sqrt(128), folded into Q weights/bias

typedef short s8v __attribute__((ext_vector_type(8)));    // 8 bf16 MFMA A/B frag
typedef float f4v __attribute__((ext_vector_type(4)));    // 16x16 C frag
typedef float f16v __attribute__((ext_vector_type(16)));  // 32x32 C frag
typedef unsigned int u32;
typedef unsigned int u2v __attribute__((ext_vector_type(2)));
typedef __attribute__((address_space(1))) const u32* gp1_t;
typedef __attribute__((address_space(3))) u32* lp3_t;

__device__ __forceinline__ ushort f2bf(float f) {
  union { float f; unsigned u; } v; v.f = f;
  unsigned r = v.u + 0x7fffu + ((v.u >> 16) & 1u);  // RNE
  return (ushort)(r >> 16);
}
__device__ __forceinline__ float bf2f(ushort h) {
  union { unsigned u; float f; } v; v.u = ((unsigned)h) << 16; return v.f;
}
__device__ __forceinline__ void gload_lds16(const void* g, void* l) {
  __builtin_amdgcn_global_load_lds((gp1_t)g, (lp3_t)l, 16, 0, 0);
}
__device__ __forceinline__ u32 cvtpk(float lo, float hi) {
  u32 r;
  asm("v_cvt_pk_bf16_f32 %0, %1, %2" : "=v"(r) : "v"(lo), "v"(hi));
  return r;
}
// split 8 consecutive fp32 into bf16 hi + lo fragments (bf16x3 accuracy)
__device__ __forceinline__ void split8(const float* __restrict__ p, float scale,
                                       s8v& hi, s8v& lo) {
  union { s8v v; ushort u[8]; } H, L;
  #pragma unroll
  for (int i = 0; i < 8; ++i) {
    float v = p[i] * scale;
    ushort h = f2bf(v);
    H.u[i] = h;
    L.u[i] = f2bf(v - bf2f(h));
  }
  hi = H.v; lo = L.v;
}

// ---------------- projection as bf16x3 MFMA GEMM ---------------------------
__global__ __launch_bounds__(256, 2) void proj_gemm(
    const float* __restrict__ x,
    const float* __restrict__ Wq, const float* __restrict__ bq,
    const float* __restrict__ Wk, const float* __restrict__ bk,
    const float* __restrict__ Wv, const float* __restrict__ bv,
    ushort* __restrict__ Qn, ushort* __restrict__ Kn, ushort* __restrict__ Vt)
{
  const int tid = threadIdx.x;
  const int wv = tid >> 6, lane = tid & 63;
  const int g = lane >> 4, c = lane & 15;
  const int bid = blockIdx.x;
  const int b = bid & 7;                  // XCD pin
  const int s0 = (bid >> 3) * 64;
  const float* xb = x + (size_t)b * NE * NS;

  __shared__ __align__(16) ushort xh[64][136], xl[64][136];  // x^T tile, hi/lo

  {
    const int ss = tid & 63, cq = tid >> 6;
    #pragma unroll
    for (int p = 0; p < 4; ++p) {
      const int ch = p * 4 + cq;
      union { s8v v; ushort u[8]; } H, L;
      #pragma unroll
      for (int i = 0; i < 8; ++i) {
        float v = xb[(size_t)(ch * 8 + i) * NS + s0 + ss];
        ushort hi = f2bf(v);
        H.u[i] = hi;
        L.u[i] = f2bf(v - bf2f(hi));
      }
      *(s8v*)&xh[ss][ch * 8] = H.v;
      *(s8v*)&xl[ss][ch * 8] = L.v;
    }
  }
  __syncthreads();

  f4v aq[2][4], ak[2][4], av[2][4];
  #pragma unroll
  for (int i = 0; i < 2; ++i)
    #pragma unroll
    for (int j = 0; j < 4; ++j) {
      aq[i][j] = (f4v){0.f,0.f,0.f,0.f};
      ak[i][j] = (f4v){0.f,0.f,0.f,0.f};
      av[i][j] = (f4v){0.f,0.f,0.f,0.f};
    }

  #pragma unroll
  for (int ks = 0; ks < 4; ++ks) {
    s8v xbh[4], xbl[4];
    #pragma unroll
    for (int st = 0; st < 4; ++st) {
      xbh[st] = *(const s8v*)&xh[st * 16 + c][ks * 32 + g * 8];
      xbl[st] = *(const s8v*)&xl[st * 16 + c][ks * 32 + g * 8];
    }
    #pragma unroll
    for (int ftl = 0; ftl < 2; ++ftl) {
      const int f0 = (wv * 2 + ftl) * 16;
      const size_t wo = (size_t)(f0 + c) * NE + ks * 32 + g * 8;
      s8v qh, ql, kh, kl, vh, vl;
      split8(Wq + wo, CSCALE, qh, ql);
      split8(Wk + wo, 1.0f,   kh, kl);
      split8(Wv + wo, 1.0f,   vh, vl);
      #pragma unroll
      for (int st = 0; st < 4; ++st) {
        aq[ftl][st] = __builtin_amdgcn_mfma_f32_16x16x32_bf16(xbh[st], qh, aq[ftl][st], 0, 0, 0);
        aq[ftl][st] = __builtin_amdgcn_mfma_f32_16x16x32_bf16(xbl[st], qh, aq[ftl][st], 0, 0, 0);
        aq[ftl][st] = __builtin_amdgcn_mfma_f32_16x16x32_bf16(xbh[st], ql, aq[ftl][st], 0, 0, 0);
        av[ftl][st] = __builtin_amdgcn_mfma_f32_16x16x32_bf16(vh, xbh[st], av[ftl][st], 0, 0, 0);
        av[ftl][st] = __builtin_amdgcn_mfma_f32_16x16x32_bf16(vh, xbl[st], av[ftl][st], 0, 0, 0);
        av[ftl][st] = __builtin_amdgcn_mfma_f32_16x16x32_bf16(vl, xbh[st], av[ftl][st], 0, 0, 0);
        ak[ftl][st] = __builtin_amdgcn_mfma_f32_16x16x32_bf16(xbh[st], kh, ak[ftl][st], 0, 0, 0);
        ak[ftl][st] = __builtin_amdgcn_mfma_f32_16x16x32_bf16(xbl[st], kh, ak[ftl][st], 0, 0, 0);
        ak[ftl][st] = __builtin_amdgcn_mfma_f32_16x16x32_bf16(xbh[st], kl, ak[ftl][st], 0, 0, 0);
      }
    }
  }

  ushort* Qnb = Qn + (size_t)b * NS * NE;
  ushort* Knb = Kn + (size_t)b * NS * NE;
  ushort* Vtb = Vt + (size_t)b * NE * NS;
  #pragma unroll
  for (int ftl = 0; ftl < 2; ++ftl) {
    const int f0 = (wv * 2 + ftl) * 16;
    #pragma unroll
    for (int r = 0; r < 4; ++r) {
      const int f = f0 + 4 * g + r;
      const float bvv = bv[f];
      #pragma unroll
      for (int st = 0; st < 4; ++st)
        Vtb[(size_t)f * NS + s0 + st * 16 + c] = f2bf(av[ftl][st][r] + bvv);
    }
    const float bqv = bq[f0 + c] * CSCALE;
    const float bkv = bk[f0 + c];
    #pragma unroll
    for (int st = 0; st < 4; ++st)
      #pragma unroll
      for (int r = 0; r < 4; ++r) {
        const size_t ro = (size_t)(s0 + st * 16 + 4 * g + r) * NE + f0 + c;
        Qnb[ro] = f2bf(aq[ftl][st][r] + bqv);
        Knb[ro] = f2bf(ak[ftl][st][r] + bkv);
      }
  }
}

// ------- flash attention: 8 warps = 2 q-subs x 4 k-slices, QW=64, KVB=32 ---
// Each wave owns 64 q (2 subtiles sharing every K/V fragment -> 2 MFMA per
// ds_read). K [32 k][256B] xor16; V quad-pack [32 rows][256B] xor16 (row r
// quarter j holds d=r+32j, k 0..31) -> both read with row=q5 + xor16 (the
// class measured conflict-free in R14). Dbuf, staged 1-ahead; 4-slice
// sequential combine (R10-proven).
__global__ __launch_bounds__(512, 2) void attn_kernel(
    const ushort* __restrict__ Qn, const ushort* __restrict__ Kn,
    const ushort* __restrict__ Vt, float* __restrict__ out)
{
  const int tid = threadIdx.x;
  const int w = tid >> 6, lane = tid & 63;
  const int h = lane >> 5, q5 = lane & 31;
  const int slice = w >> 1;                    // k-slice (0..3), 1024 k each
  const int sub = w & 1;                       // q-half within block
  const int bid = blockIdx.x;
  const int b = bid & 7;                       // XCD pin
  const int qw = (bid >> 3) * 128 + sub * 64;  // wave's 64-q strip

  const ushort* Qb = Qn + (size_t)b * NS * NE;
  const char*   Kb = (const char*)(Kn + (size_t)b * NS * NE);
  const char*   Vb = (const char*)(Vt + (size_t)b * NE * NS);

  __shared__ __align__(16) char lds[131072];   // [slice][buf][K 8K | V 8K]
  __shared__ float lx[4][2][2][32];            // [slice][sub][u][q5] lsum

  auto Kbuf = [&](int bf) -> char* { return lds + slice * 32768 + bf * 16384; };
  auto Vbuf = [&](int bf) -> char* { return Kbuf(bf) + 8192; };

  // Q B-frags for both 32-q subtiles: lane holds Q[q][dc*16 + h*8 + j]
  s8v qfA[8], qfB[8];
  #pragma unroll
  for (int dc = 0; dc < 8; ++dc) {
    qfA[dc] = *(const s8v*)(Qb + (size_t)(qw + q5) * NE + dc * 16 + h * 8);
    qfB[dc] = *(const s8v*)(Qb + (size_t)(qw + 32 + q5) * NE + dc * 16 + h * 8);
  }

  // stage tile t of own slice: sub0 -> K (8KB), sub1 -> V (8KB)
  auto stage = [&](int bf, int t) {
    const int kt = slice * 32 + t;
    if (sub == 0) {
      const char* Ksrc = Kb + (size_t)kt * 8192;   // contiguous 8KB
      char* dst = Kbuf(bf);
      #pragma unroll
      for (int p = 0; p < 8; ++p) {
        const int off = p * 1024;
        const int lo = off + lane * 16;
        const int row = lo >> 8;                   // k row (256B)
        gload_lds16(Ksrc + (lo ^ ((row & 15) << 4)), dst + off);
      }
    } else {
      // V quad-pack: row r, quarter j (64B) holds d = r + 32j, k 0..31
      char* dst = Vbuf(bf);
      #pragma unroll
      for (int p = 0; p < 8; ++p) {
        const int off = p * 1024;
        const int lo = off + lane * 16;
        const int row = lo >> 8;
        const int inner = (lo & 255) ^ ((row & 15) << 4);
        const int d = row + 32 * (inner >> 6);
        gload_lds16(Vb + (size_t)d * (NS * 2) + kt * 64 + (inner & 63), dst + off);
      }
    }
  };

  // fused exp2 -> bf16 PV B-frag (8 scores -> one frag, sums into l)
  auto expfrag8 = [&](float a0, float a1, float a2, float a3,
                      float a4, float a5, float a6, float a7, float& l) -> s8v {
    float p0 = __builtin_amdgcn_exp2f(a0), p1 = __builtin_amdgcn_exp2f(a1);
    float p2 = __builtin_amdgcn_exp2f(a2), p3 = __builtin_amdgcn_exp2f(a3);
    float p4 = __builtin_amdgcn_exp2f(a4), p5 = __builtin_amdgcn_exp2f(a5);
    float p6 = __builtin_amdgcn_exp2f(a6), p7 = __builtin_amdgcn_exp2f(a7);
    l += ((p0 + p1) + (p2 + p3)) + ((p4 + p5) + (p6 + p7));
    u32 A = cvtpk(p0, p1);
    u32 B = cvtpk(p4, p5);
    u32 C = cvtpk(p2, p3);
    u32 D = cvtpk(p6, p7);
    u2v rAB = __builtin_amdgcn_permlane32_swap(A, B, false, false);
    u2v rCD = __builtin_amdgcn_permlane32_swap(C, D, false, false);
    union { s8v v; u32 wd[4]; } P;
    P.wd[0] = rAB[0]; P.wd[1] = rCD[0]; P.wd[2] = rAB[1]; P.wd[3] = rCD[1];
    return P.v;
  };

  f16v oA[4], oB[4];
  #pragma unroll
  for (int dt = 0; dt < 4; ++dt) {
    oA[dt] = (f16v){0,0,0,0,0,0,0,0,0,0,0,0,0,0,0,0};
    oB[dt] = (f16v){0,0,0,0,0,0,0,0,0,0,0,0,0,0,0,0};
  }
  float lA = 0.f, lB = 0.f;

  stage(0, 0);
  asm volatile("s_waitcnt vmcnt(0)" ::: "memory");
  __builtin_amdgcn_sched_barrier(0);
  __builtin_amdgcn_s_barrier();

  #pragma unroll 1
  for (int t = 0; t < 32; ++t) {
    const int cur = t & 1;
    if (t + 1 < 32) stage(cur ^ 1, t + 1);   // drained at end-of-tile vmcnt
    const char* bK = Kbuf(cur);
    const char* bV = Vbuf(cur);

    // ---- QK: S^T[k 0..31][q] for both q-subtiles (K frag shared)
    f16v sA = (f16v){0,0,0,0,0,0,0,0,0,0,0,0,0,0,0,0};
    f16v sB = (f16v){0,0,0,0,0,0,0,0,0,0,0,0,0,0,0,0};
    __builtin_amdgcn_s_setprio(1);
    #pragma unroll
    for (int dc = 0; dc < 8; ++dc) {
      s8v kf = *(const s8v*)(bK + q5 * 256 + ((dc * 32 + h * 16) ^ ((q5 & 15) << 4)));
      sA = __builtin_amdgcn_mfma_f32_32x32x16_bf16(kf, qfA[dc], sA, 0, 0, 0);
      sB = __builtin_amdgcn_mfma_f32_32x32x16_bf16(kf, qfB[dc], sB, 0, 0, 0);
    }
    __builtin_amdgcn_s_setprio(0);

    // ---- SM: scores -> P frags (2 ks-groups x 2 subtiles)
    s8v PA0 = expfrag8(sA[0], sA[1], sA[2], sA[3], sA[4], sA[5], sA[6], sA[7], lA);
    s8v PA1 = expfrag8(sA[8], sA[9], sA[10], sA[11], sA[12], sA[13], sA[14], sA[15], lA);
    s8v PB0 = expfrag8(sB[0], sB[1], sB[2], sB[3], sB[4], sB[5], sB[6], sB[7], lB);
    s8v PB1 = expfrag8(sB[8], sB[9], sB[10], sB[11], sB[12], sB[13], sB[14], sB[15], lB);

    // ---- PV: O^T[d][q] += V^T . P  (V frag shared by both subtiles)
    __builtin_amdgcn_s_setprio(1);
    #pragma unroll
    for (int dt = 0; dt < 4; ++dt) {
      s8v vf0 = *(const s8v*)(bV + q5 * 256 + ((dt * 64 + h * 16)      ^ ((q5 & 15) << 4)));
      s8v vf1 = *(const s8v*)(bV + q5 * 256 + ((dt * 64 + 32 + h * 16) ^ ((q5 & 15) << 4)));
      oA[dt] = __builtin_amdgcn_mfma_f32_32x32x16_bf16(vf0, PA0, oA[dt], 0, 0, 0);
      oB[dt] = __builtin_amdgcn_mfma_f32_32x32x16_bf16(vf0, PB0, oB[dt], 0, 0, 0);
      oA[dt] = __builtin_amdgcn_mfma_f32_32x32x16_bf16(vf1, PA1, oA[dt], 0, 0, 0);
      oB[dt] = __builtin_amdgcn_mfma_f32_32x32x16_bf16(vf1, PB1, oB[dt], 0, 0, 0);
    }
    __builtin_amdgcn_s_setprio(0);

    // ---- end of tile: my ds_reads done; next tile resident; converge
    asm volatile("s_waitcnt lgkmcnt(0)" ::: "memory");
    __builtin_amdgcn_sched_barrier(0);
    asm volatile("s_waitcnt vmcnt(0)" ::: "memory");   // issued a full tile ago
    __builtin_amdgcn_sched_barrier(0);
    __builtin_amdgcn_s_barrier();
  }

  // ---- 4-slice sequential combine via dead LDS (R10-proven) ---------------
  lA += __shfl_xor(lA, 32);
  lB += __shfl_xor(lB, 32);
  if (h == 0) { lx[slice][sub][0][q5] = lA; lx[slice][sub][1][q5] = lB; }
  float* cb = (float*)lds;                 // [sub][128 e][64 q] = 64 KB
  const int base = sub * 8192;
  __syncthreads();
  if (slice == 0) {                        // init with slice 0's partial
    #pragma unroll
    for (int dt = 0; dt < 4; ++dt)
      #pragma unroll
      for (int r = 0; r < 16; ++r) {
        const int e = dt * 32 + (r & 3) + 8 * (r >> 2) + 4 * h;
        cb[base + e * 64 + q5]      = oA[dt][r];
        cb[base + e * 64 + 32 + q5] = oB[dt][r];
      }
  }
  __syncthreads();
  #pragma unroll 1
  for (int sl = 1; sl < 4; ++sl) {         // barrier-ordered accumulation
    if (slice == sl) {
      #pragma unroll
      for (int dt = 0; dt < 4; ++dt)
        #pragma unroll
        for (int r = 0; r < 16; ++r) {
          const int e = dt * 32 + (r & 3) + 8 * (r >> 2) + 4 * h;
          cb[base + e * 64 + q5]      += oA[dt][r];
          cb[base + e * 64 + 32 + q5] += oB[dt][r];
        }
    }
    __syncthreads();
  }
  if (slice == 0) {                        // normalize + store
    const float rA = 1.0f / (lx[0][sub][0][q5] + lx[1][sub][0][q5] +
                             lx[2][sub][0][q5] + lx[3][sub][0][q5]);
    const float rB = 1.0f / (lx[0][sub][1][q5] + lx[1][sub][1][q5] +
                             lx[2][sub][1][q5] + lx[3][sub][1][q5]);
    float* ob = out + (size_t)b * NE * NS;
    #pragma unroll
    for (int dt = 0; dt < 4; ++dt)
      #pragma unroll
      for (int r = 0; r < 16; ++r) {
        const int e = dt * 32 + (r & 3) + 8 * (r >> 2) + 4 * h;
        ob[(size_t)e * NS + qw + q5]      = cb[base + e * 64 + q5] * rA;
        ob[(size_t)e * NS + qw + 32 + q5] = cb[base + e * 64 + 32 + q5] * rB;
      }
  }
}

extern "C" void kernel_launch(void* const* d_in, const int* in_sizes, int n_in,
                              void* d_out, int out_size, void* d_ws, size_t ws_size,
                              hipStream_t stream) {
  (void)in_sizes; (void)n_in; (void)out_size; (void)ws_size;
  const float* x  = (const float*)d_in[0];
  const float* Wq = (const float*)d_in[1];
  const float* bq = (const float*)d_in[2];
  const float* Wk = (const float*)d_in[3];
  const float* bk = (const float*)d_in[4];
  const float* Wv = (const float*)d_in[5];
  const float* bv = (const float*)d_in[6];
  float* out = (float*)d_out;

  ushort* Qn = (ushort*)d_ws;                      // [B][S][D] bf16, 8 MB
  ushort* Kn = Qn + (size_t)NB * NS * NE;          // [B][S][D] bf16, 8 MB
  ushort* Vt = Kn + (size_t)NB * NS * NE;          // [B][D][S] bf16, 8 MB

  proj_gemm<<<dim3(NS / 64 * NB), 256, 0, stream>>>(x, Wq, bq, Wk, bk, Wv, bv, Qn, Kn, Vt);
  attn_kernel<<<dim3(NS / 128 * NB), 512, 0, stream>>>(Qn, Kn, Vt, out);
}

// Round 16
// 131.656 us; speedup vs baseline: 1.3026x; 1.3026x over previous
//
#include <hip/hip_runtime.h>
#include <math.h>

#define NB 8
#define NE 128
#define NS 4096
#define CSCALE 0.12751743f   // log2(e)/sqrt(128), folded into Q weights/bias

typedef short s8v __attribute__((ext_vector_type(8)));    // 8 bf16 MFMA A/B frag
typedef float f4v __attribute__((ext_vector_type(4)));    // 16x16 C frag
typedef float f16v __attribute__((ext_vector_type(16)));  // 32x32 C frag
typedef unsigned int u32;
typedef unsigned int u2v __attribute__((ext_vector_type(2)));
typedef __attribute__((address_space(1))) const u32* gp1_t;
typedef __attribute__((address_space(3))) u32* lp3_t;

__device__ __forceinline__ ushort f2bf(float f) {
  union { float f; unsigned u; } v; v.f = f;
  unsigned r = v.u + 0x7fffu + ((v.u >> 16) & 1u);  // RNE
  return (ushort)(r >> 16);
}
__device__ __forceinline__ float bf2f(ushort h) {
  union { unsigned u; float f; } v; v.u = ((unsigned)h) << 16; return v.f;
}
__device__ __forceinline__ void gload_lds16(const void* g, void* l) {
  __builtin_amdgcn_global_load_lds((gp1_t)g, (lp3_t)l, 16, 0, 0);
}
__device__ __forceinline__ u32 cvtpk(float lo, float hi) {
  u32 r;
  asm("v_cvt_pk_bf16_f32 %0, %1, %2" : "=v"(r) : "v"(lo), "v"(hi));
  return r;
}
// split 8 consecutive fp32 into bf16 hi + lo fragments (bf16x3 accuracy)
__device__ __forceinline__ void split8(const float* __restrict__ p, float scale,
                                       s8v& hi, s8v& lo) {
  union { s8v v; ushort u[8]; } H, L;
  #pragma unroll
  for (int i = 0; i < 8; ++i) {
    float v = p[i] * scale;
    ushort h = f2bf(v);
    H.u[i] = h;
    L.u[i] = f2bf(v - bf2f(h));
  }
  hi = H.v; lo = L.v;
}

// ---------------- projection as bf16x3 MFMA GEMM ---------------------------
__global__ __launch_bounds__(256, 2) void proj_gemm(
    const float* __restrict__ x,
    const float* __restrict__ Wq, const float* __restrict__ bq,
    const float* __restrict__ Wk, const float* __restrict__ bk,
    const float* __restrict__ Wv, const float* __restrict__ bv,
    ushort* __restrict__ Qn, ushort* __restrict__ Kn, ushort* __restrict__ Vt)
{
  const int tid = threadIdx.x;
  const int wv = tid >> 6, lane = tid & 63;
  const int g = lane >> 4, c = lane & 15;
  const int bid = blockIdx.x;
  const int b = bid & 7;                  // XCD pin
  const int s0 = (bid >> 3) * 64;
  const float* xb = x + (size_t)b * NE * NS;

  __shared__ __align__(16) ushort xh[64][136], xl[64][136];  // x^T tile, hi/lo

  {
    const int ss = tid & 63, cq = tid >> 6;
    #pragma unroll
    for (int p = 0; p < 4; ++p) {
      const int ch = p * 4 + cq;
      union { s8v v; ushort u[8]; } H, L;
      #pragma unroll
      for (int i = 0; i < 8; ++i) {
        float v = xb[(size_t)(ch * 8 + i) * NS + s0 + ss];
        ushort hi = f2bf(v);
        H.u[i] = hi;
        L.u[i] = f2bf(v - bf2f(hi));
      }
      *(s8v*)&xh[ss][ch * 8] = H.v;
      *(s8v*)&xl[ss][ch * 8] = L.v;
    }
  }
  __syncthreads();

  f4v aq[2][4], ak[2][4], av[2][4];
  #pragma unroll
  for (int i = 0; i < 2; ++i)
    #pragma unroll
    for (int j = 0; j < 4; ++j) {
      aq[i][j] = (f4v){0.f,0.f,0.f,0.f};
      ak[i][j] = (f4v){0.f,0.f,0.f,0.f};
      av[i][j] = (f4v){0.f,0.f,0.f,0.f};
    }

  #pragma unroll
  for (int ks = 0; ks < 4; ++ks) {
    s8v xbh[4], xbl[4];
    #pragma unroll
    for (int st = 0; st < 4; ++st) {
      xbh[st] = *(const s8v*)&xh[st * 16 + c][ks * 32 + g * 8];
      xbl[st] = *(const s8v*)&xl[st * 16 + c][ks * 32 + g * 8];
    }
    #pragma unroll
    for (int ftl = 0; ftl < 2; ++ftl) {
      const int f0 = (wv * 2 + ftl) * 16;
      const size_t wo = (size_t)(f0 + c) * NE + ks * 32 + g * 8;
      s8v qh, ql, kh, kl, vh, vl;
      split8(Wq + wo, CSCALE, qh, ql);
      split8(Wk + wo, 1.0f,   kh, kl);
      split8(Wv + wo, 1.0f,   vh, vl);
      #pragma unroll
      for (int st = 0; st < 4; ++st) {
        aq[ftl][st] = __builtin_amdgcn_mfma_f32_16x16x32_bf16(xbh[st], qh, aq[ftl][st], 0, 0, 0);
        aq[ftl][st] = __builtin_amdgcn_mfma_f32_16x16x32_bf16(xbl[st], qh, aq[ftl][st], 0, 0, 0);
        aq[ftl][st] = __builtin_amdgcn_mfma_f32_16x16x32_bf16(xbh[st], ql, aq[ftl][st], 0, 0, 0);
        av[ftl][st] = __builtin_amdgcn_mfma_f32_16x16x32_bf16(vh, xbh[st], av[ftl][st], 0, 0, 0);
        av[ftl][st] = __builtin_amdgcn_mfma_f32_16x16x32_bf16(vh, xbl[st], av[ftl][st], 0, 0, 0);
        av[ftl][st] = __builtin_amdgcn_mfma_f32_16x16x32_bf16(vl, xbh[st], av[ftl][st], 0, 0, 0);
        ak[ftl][st] = __builtin_amdgcn_mfma_f32_16x16x32_bf16(xbh[st], kh, ak[ftl][st], 0, 0, 0);
        ak[ftl][st] = __builtin_amdgcn_mfma_f32_16x16x32_bf16(xbl[st], kh, ak[ftl][st], 0, 0, 0);
        ak[ftl][st] = __builtin_amdgcn_mfma_f32_16x16x32_bf16(xbh[st], kl, ak[ftl][st], 0, 0, 0);
      }
    }
  }

  ushort* Qnb = Qn + (size_t)b * NS * NE;
  ushort* Knb = Kn + (size_t)b * NS * NE;
  ushort* Vtb = Vt + (size_t)b * NE * NS;
  #pragma unroll
  for (int ftl = 0; ftl < 2; ++ftl) {
    const int f0 = (wv * 2 + ftl) * 16;
    #pragma unroll
    for (int r = 0; r < 4; ++r) {
      const int f = f0 + 4 * g + r;
      const float bvv = bv[f];
      #pragma unroll
      for (int st = 0; st < 4; ++st)
        Vtb[(size_t)f * NS + s0 + st * 16 + c] = f2bf(av[ftl][st][r] + bvv);
    }
    const float bqv = bq[f0 + c] * CSCALE;
    const float bkv = bk[f0 + c];
    #pragma unroll
    for (int st = 0; st < 4; ++st)
      #pragma unroll
      for (int r = 0; r < 4; ++r) {
        const size_t ro = (size_t)(s0 + st * 16 + 4 * g + r) * NE + f0 + c;
        Qnb[ro] = f2bf(aq[ftl][st][r] + bqv);
        Knb[ro] = f2bf(ak[ftl][st][r] + bkv);
      }
  }
}

// ------- flash attention: 4 waves = 4 k-slices x same 64-q strip -----------
// QW=64 (2 subtiles share every K/V frag -> 2 MFMA per ds_read), KVB=32,
// 1 wave/SIMD (512-reg budget, no spill). Wave-private dbuf K/V tiles,
// barrier-free k-loop with split-issue counted vmcnt; PV(t-1) pipelined
// so SM(t) hides in its MFMA shadow. R12-proven combine epilogue.
__global__ __launch_bounds__(256, 1) void attn_kernel(
    const ushort* __restrict__ Qn, const ushort* __restrict__ Kn,
    const ushort* __restrict__ Vt, float* __restrict__ out)
{
  const int tid = threadIdx.x;
  const int w = tid >> 6, lane = tid & 63;
  const int h = lane >> 5, q5 = lane & 31;
  const int slice = w;                         // k-slice (0..3), 1024 k each
  const int bid = blockIdx.x;
  const int b = bid & 7;                       // XCD pin: batch b -> XCD b
  const int qw = (bid >> 3) * 64;              // block's 64-q strip (shared)

  const ushort* Qb = Qn + (size_t)b * NS * NE;
  const char*   Kb = (const char*)(Kn + (size_t)b * NS * NE);
  const char*   Vb = (const char*)(Vt + (size_t)b * NE * NS);

  __shared__ __align__(16) char lds[131072];   // 4 waves x [K dbuf 16K | V dbuf 16K]
  __shared__ float lx[4][2][32];               // [slice][u][q5] lsum

  auto Kbuf = [&](int bf) -> char* { return lds + w * 32768 + bf * 8192; };
  auto Vbuf = [&](int bf) -> char* { return lds + w * 32768 + 16384 + bf * 8192; };

  // Q B-frags for both 32-q subtiles: lane holds Q[q][dc*16 + h*8 + j]
  s8v qfA[8], qfB[8];
  #pragma unroll
  for (int dc = 0; dc < 8; ++dc) {
    qfA[dc] = *(const s8v*)(Qb + (size_t)(qw + q5) * NE + dc * 16 + h * 8);
    qfB[dc] = *(const s8v*)(Qb + (size_t)(qw + 32 + q5) * NE + dc * 16 + h * 8);
  }

  // K tile [32 k][256B] xor16 (proven); 8 gload_lds
  auto stageK = [&](int bf, int t) {
    const int kt = slice * 32 + t;
    const char* Ksrc = Kb + (size_t)kt * 8192;   // contiguous 8KB
    char* dst = Kbuf(bf);
    #pragma unroll
    for (int p = 0; p < 8; ++p) {
      const int off = p * 1024;
      const int lo = off + lane * 16;
      const int row = lo >> 8;
      gload_lds16(Ksrc + (lo ^ ((row & 15) << 4)), dst + off);
    }
  };
  // V quad-pack [32 rows][256B] xor16 (R15-proven, 0 conflicts): row r
  // quarter j (64B) holds d = r + 32j, k 0..31; 8 gload_lds
  auto stageV = [&](int bf, int t) {
    const int kt = slice * 32 + t;
    char* dst = Vbuf(bf);
    #pragma unroll
    for (int p = 0; p < 8; ++p) {
      const int off = p * 1024;
      const int lo = off + lane * 16;
      const int row = lo >> 8;
      const int inner = (lo & 255) ^ ((row & 15) << 4);
      const int d = row + 32 * (inner >> 6);
      gload_lds16(Vb + (size_t)d * (NS * 2) + kt * 64 + (inner & 63), dst + off);
    }
  };

  // fused exp2 -> bf16 PV B-frag (8 scores -> one frag, sums into l)
  auto expfrag8 = [&](float a0, float a1, float a2, float a3,
                      float a4, float a5, float a6, float a7, float& l) -> s8v {
    float p0 = __builtin_amdgcn_exp2f(a0), p1 = __builtin_amdgcn_exp2f(a1);
    float p2 = __builtin_amdgcn_exp2f(a2), p3 = __builtin_amdgcn_exp2f(a3);
    float p4 = __builtin_amdgcn_exp2f(a4), p5 = __builtin_amdgcn_exp2f(a5);
    float p6 = __builtin_amdgcn_exp2f(a6), p7 = __builtin_amdgcn_exp2f(a7);
    l += ((p0 + p1) + (p2 + p3)) + ((p4 + p5) + (p6 + p7));
    u32 A = cvtpk(p0, p1);
    u32 B = cvtpk(p4, p5);
    u32 C = cvtpk(p2, p3);
    u32 D = cvtpk(p6, p7);
    u2v rAB = __builtin_amdgcn_permlane32_swap(A, B, false, false);
    u2v rCD = __builtin_amdgcn_permlane32_swap(C, D, false, false);
    union { s8v v; u32 wd[4]; } P;
    P.wd[0] = rAB[0]; P.wd[1] = rCD[0]; P.wd[2] = rAB[1]; P.wd[3] = rCD[1];
    return P.v;
  };

  // PV(t-1): V frag shared by both q-subtiles -> 2 MFMA per ds_read
  auto pvtile = [&](const char* bV, s8v PA0, s8v PA1, s8v PB0, s8v PB1,
                    f16v* oA, f16v* oB) {
    __builtin_amdgcn_s_setprio(1);
    #pragma unroll
    for (int dt = 0; dt < 4; ++dt) {
      s8v vf0 = *(const s8v*)(bV + q5 * 256 + ((dt * 64 + h * 16)      ^ ((q5 & 15) << 4)));
      s8v vf1 = *(const s8v*)(bV + q5 * 256 + ((dt * 64 + 32 + h * 16) ^ ((q5 & 15) << 4)));
      oA[dt] = __builtin_amdgcn_mfma_f32_32x32x16_bf16(vf0, PA0, oA[dt], 0, 0, 0);
      oB[dt] = __builtin_amdgcn_mfma_f32_32x32x16_bf16(vf0, PB0, oB[dt], 0, 0, 0);
      oA[dt] = __builtin_amdgcn_mfma_f32_32x32x16_bf16(vf1, PA1, oA[dt], 0, 0, 0);
      oB[dt] = __builtin_amdgcn_mfma_f32_32x32x16_bf16(vf1, PB1, oB[dt], 0, 0, 0);
    }
    __builtin_amdgcn_s_setprio(0);
  };

  f16v oA[4], oB[4];
  #pragma unroll
  for (int dt = 0; dt < 4; ++dt) {
    oA[dt] = (f16v){0,0,0,0,0,0,0,0,0,0,0,0,0,0,0,0};
    oB[dt] = (f16v){0,0,0,0,0,0,0,0,0,0,0,0,0,0,0,0};
  }
  float lA = 0.f, lB = 0.f;
  s8v PpA0 = (s8v){0,0,0,0,0,0,0,0}, PpA1 = PpA0, PpB0 = PpA0, PpB1 = PpA0;

  // prologue: tile 0 K+V (16 loads in flight)
  stageK(0, 0);
  stageV(0, 0);

  #pragma unroll 1
  for (int t = 0; t < 32; ++t) {
    const int tn = (t + 1 < 32) ? t + 1 : 31;   // uniform re-issue keeps counts
    stageK((t + 1) & 1, tn);                    // +8 (K(t+1))

    // wait: all but the 16 newest (V(t)-or-older drained next iter; K(t) ready)
    asm volatile("s_waitcnt vmcnt(16)" ::: "memory");
    __builtin_amdgcn_sched_barrier(0);

    // ---- QK(t): S^T[k][q] for both q-subtiles (K frag shared)
    const char* bK = Kbuf(t & 1);
    f16v sA = (f16v){0,0,0,0,0,0,0,0,0,0,0,0,0,0,0,0};
    f16v sB = (f16v){0,0,0,0,0,0,0,0,0,0,0,0,0,0,0,0};
    __builtin_amdgcn_s_setprio(1);
    #pragma unroll
    for (int dc = 0; dc < 8; ++dc) {
      s8v kf = *(const s8v*)(bK + q5 * 256 + ((dc * 32 + h * 16) ^ ((q5 & 15) << 4)));
      sA = __builtin_amdgcn_mfma_f32_32x32x16_bf16(kf, qfA[dc], sA, 0, 0, 0);
      sB = __builtin_amdgcn_mfma_f32_32x32x16_bf16(kf, qfB[dc], sB, 0, 0, 0);
    }
    __builtin_amdgcn_s_setprio(0);

    // ---- PV(t-1): independent MFMA stream; SM(t) fills its issue shadow
    if (t > 0) pvtile(Vbuf((t - 1) & 1), PpA0, PpA1, PpB0, PpB1, oA, oB);

    // ---- SM(t): scores -> P frags for next tile's PV
    PpA0 = expfrag8(sA[0], sA[1], sA[2], sA[3], sA[4], sA[5], sA[6], sA[7], lA);
    PpA1 = expfrag8(sA[8], sA[9], sA[10], sA[11], sA[12], sA[13], sA[14], sA[15], lA);
    PpB0 = expfrag8(sB[0], sB[1], sB[2], sB[3], sB[4], sB[5], sB[6], sB[7], lB);
    PpB1 = expfrag8(sB[8], sB[9], sB[10], sB[11], sB[12], sB[13], sB[14], sB[15], lB);

    // my ds_reads (incl. PV(t-1) reads of vbuf (t+1)&1's alias) are done
    asm volatile("s_waitcnt lgkmcnt(0)" ::: "memory");
    __builtin_amdgcn_sched_barrier(0);
    stageV((t + 1) & 1, tn);                    // +8 (V(t+1))
  }

  // ---- epilogue PV(31): V(31) in vbuf 1 (staged iter 30; untouched since)
  asm volatile("s_waitcnt vmcnt(0)" ::: "memory");
  __builtin_amdgcn_sched_barrier(0);
  pvtile(Vbuf(1), PpA0, PpA1, PpB0, PpB1, oA, oB);

  // ---- 4-slice sequential combine via dead LDS (R12-proven) ---------------
  lA += __shfl_xor(lA, 32);
  lB += __shfl_xor(lB, 32);
  if (h == 0) { lx[slice][0][q5] = lA; lx[slice][1][q5] = lB; }
  float* cb = (float*)lds;                 // [128 e][64 q] f32 = 32 KB
  __syncthreads();                         // all waves done with their tiles
  if (slice == 0) {                        // init with slice 0's partial
    #pragma unroll
    for (int dt = 0; dt < 4; ++dt)
      #pragma unroll
      for (int r = 0; r < 16; ++r) {
        const int e = dt * 32 + (r & 3) + 8 * (r >> 2) + 4 * h;
        cb[e * 64 + q5]      = oA[dt][r];
        cb[e * 64 + 32 + q5] = oB[dt][r];
      }
  }
  __syncthreads();
  #pragma unroll 1
  for (int sl = 1; sl < 4; ++sl) {         // barrier-ordered accumulation
    if (slice == sl) {
      #pragma unroll
      for (int dt = 0; dt < 4; ++dt)
        #pragma unroll
        for (int r = 0; r < 16; ++r) {
          const int e = dt * 32 + (r & 3) + 8 * (r >> 2) + 4 * h;
          cb[e * 64 + q5]      += oA[dt][r];
          cb[e * 64 + 32 + q5] += oB[dt][r];
        }
    }
    __syncthreads();
  }
  if (slice == 0) {                        // normalize + store
    const float rA = 1.0f / (lx[0][0][q5] + lx[1][0][q5] +
                             lx[2][0][q5] + lx[3][0][q5]);
    const float rB = 1.0f / (lx[0][1][q5] + lx[1][1][q5] +
                             lx[2][1][q5] + lx[3][1][q5]);
    float* ob = out + (size_t)b * NE * NS;
    #pragma unroll
    for (int dt = 0; dt < 4; ++dt)
      #pragma unroll
      for (int r = 0; r < 16; ++r) {
        const int e = dt * 32 + (r & 3) + 8 * (r >> 2) + 4 * h;
        ob[(size_t)e * NS + qw + q5]      = cb[e * 64 + q5] * rA;
        ob[(size_t)e * NS + qw + 32 + q5] = cb[e * 64 + 32 + q5] * rB;
      }
  }
}

extern "C" void kernel_launch(void* const* d_in, const int* in_sizes, int n_in,
                              void* d_out, int out_size, void* d_ws, size_t ws_size,
                              hipStream_t stream) {
  (void)in_sizes; (void)n_in; (void)out_size; (void)ws_size;
  const float* x  = (const float*)d_in[0];
  const float* Wq = (const float*)d_in[1];
  const float* bq = (const float*)d_in[2];
  const float* Wk = (const float*)d_in[3];
  const float* bk = (const float*)d_in[4];
  const float* Wv = (const float*)d_in[5];
  const float* bv = (const float*)d_in[6];
  float* out = (float*)d_out;

  ushort* Qn = (ushort*)d_ws;                      // [B][S][D] bf16, 8 MB
  ushort* Kn = Qn + (size_t)NB * NS * NE;          // [B][S][D] bf16, 8 MB
  ushort* Vt = Kn + (size_t)NB * NS * NE;          // [B][D][S] bf16, 8 MB

  proj_gemm<<<dim3(NS / 64 * NB), 256, 0, stream>>>(x, Wq, bq, Wk, bk, Wv, bv, Qn, Kn, Vt);
  attn_kernel<<<dim3(NS / 64 * NB), 256, 0, stream>>>(Qn, Kn, Vt, out);
}

// Round 17
// 108.482 us; speedup vs baseline: 1.5808x; 1.2136x over previous
//
#include <hip/hip_runtime.h>
#include <math.h>

#define NB 8
#define NE 128
#define NS 4096
#define CSCALE 0.12751743f   // log2(e)/sqrt(128), folded into Q weights/bias

typedef short s8v __attribute__((ext_vector_type(8)));    // 8 bf16 MFMA A/B frag
typedef float f4v __attribute__((ext_vector_type(4)));    // 16x16 C frag
typedef float f16v __attribute__((ext_vector_type(16)));  // 32x32 C frag
typedef unsigned int u32;
typedef unsigned int u2v __attribute__((ext_vector_type(2)));
typedef __attribute__((address_space(1))) const u32* gp1_t;
typedef __attribute__((address_space(3))) u32* lp3_t;

__device__ __forceinline__ ushort f2bf(float f) {
  union { float f; unsigned u; } v; v.f = f;
  unsigned r = v.u + 0x7fffu + ((v.u >> 16) & 1u);  // RNE
  return (ushort)(r >> 16);
}
__device__ __forceinline__ float bf2f(ushort h) {
  union { unsigned u; float f; } v; v.u = ((unsigned)h) << 16; return v.f;
}
__device__ __forceinline__ void gload_lds16(const void* g, void* l) {
  __builtin_amdgcn_global_load_lds((gp1_t)g, (lp3_t)l, 16, 0, 0);
}
__device__ __forceinline__ u32 cvtpk(float lo, float hi) {
  u32 r;
  asm("v_cvt_pk_bf16_f32 %0, %1, %2" : "=v"(r) : "v"(lo), "v"(hi));
  return r;
}
// split 8 consecutive fp32 into bf16 hi + lo fragments (bf16x3 accuracy)
__device__ __forceinline__ void split8(const float* __restrict__ p, float scale,
                                       s8v& hi, s8v& lo) {
  union { s8v v; ushort u[8]; } H, L;
  #pragma unroll
  for (int i = 0; i < 8; ++i) {
    float v = p[i] * scale;
    ushort h = f2bf(v);
    H.u[i] = h;
    L.u[i] = f2bf(v - bf2f(h));
  }
  hi = H.v; lo = L.v;
}

// ---------------- projection as bf16x3 MFMA GEMM ---------------------------
__global__ __launch_bounds__(256, 2) void proj_gemm(
    const float* __restrict__ x,
    const float* __restrict__ Wq, const float* __restrict__ bq,
    const float* __restrict__ Wk, const float* __restrict__ bk,
    const float* __restrict__ Wv, const float* __restrict__ bv,
    ushort* __restrict__ Qn, ushort* __restrict__ Kn, ushort* __restrict__ Vt)
{
  const int tid = threadIdx.x;
  const int wv = tid >> 6, lane = tid & 63;
  const int g = lane >> 4, c = lane & 15;
  const int bid = blockIdx.x;
  const int b = bid & 7;                  // XCD pin
  const int s0 = (bid >> 3) * 64;
  const float* xb = x + (size_t)b * NE * NS;

  __shared__ __align__(16) ushort xh[64][136], xl[64][136];  // x^T tile, hi/lo

  {
    const int ss = tid & 63, cq = tid >> 6;
    #pragma unroll
    for (int p = 0; p < 4; ++p) {
      const int ch = p * 4 + cq;
      union { s8v v; ushort u[8]; } H, L;
      #pragma unroll
      for (int i = 0; i < 8; ++i) {
        float v = xb[(size_t)(ch * 8 + i) * NS + s0 + ss];
        ushort hi = f2bf(v);
        H.u[i] = hi;
        L.u[i] = f2bf(v - bf2f(hi));
      }
      *(s8v*)&xh[ss][ch * 8] = H.v;
      *(s8v*)&xl[ss][ch * 8] = L.v;
    }
  }
  __syncthreads();

  f4v aq[2][4], ak[2][4], av[2][4];
  #pragma unroll
  for (int i = 0; i < 2; ++i)
    #pragma unroll
    for (int j = 0; j < 4; ++j) {
      aq[i][j] = (f4v){0.f,0.f,0.f,0.f};
      ak[i][j] = (f4v){0.f,0.f,0.f,0.f};
      av[i][j] = (f4v){0.f,0.f,0.f,0.f};
    }

  #pragma unroll
  for (int ks = 0; ks < 4; ++ks) {
    s8v xbh[4], xbl[4];
    #pragma unroll
    for (int st = 0; st < 4; ++st) {
      xbh[st] = *(const s8v*)&xh[st * 16 + c][ks * 32 + g * 8];
      xbl[st] = *(const s8v*)&xl[st * 16 + c][ks * 32 + g * 8];
    }
    #pragma unroll
    for (int ftl = 0; ftl < 2; ++ftl) {
      const int f0 = (wv * 2 + ftl) * 16;
      const size_t wo = (size_t)(f0 + c) * NE + ks * 32 + g * 8;
      s8v qh, ql, kh, kl, vh, vl;
      split8(Wq + wo, CSCALE, qh, ql);
      split8(Wk + wo, 1.0f,   kh, kl);
      split8(Wv + wo, 1.0f,   vh, vl);
      #pragma unroll
      for (int st = 0; st < 4; ++st) {
        aq[ftl][st] = __builtin_amdgcn_mfma_f32_16x16x32_bf16(xbh[st], qh, aq[ftl][st], 0, 0, 0);
        aq[ftl][st] = __builtin_amdgcn_mfma_f32_16x16x32_bf16(xbl[st], qh, aq[ftl][st], 0, 0, 0);
        aq[ftl][st] = __builtin_amdgcn_mfma_f32_16x16x32_bf16(xbh[st], ql, aq[ftl][st], 0, 0, 0);
        av[ftl][st] = __builtin_amdgcn_mfma_f32_16x16x32_bf16(vh, xbh[st], av[ftl][st], 0, 0, 0);
        av[ftl][st] = __builtin_amdgcn_mfma_f32_16x16x32_bf16(vh, xbl[st], av[ftl][st], 0, 0, 0);
        av[ftl][st] = __builtin_amdgcn_mfma_f32_16x16x32_bf16(vl, xbh[st], av[ftl][st], 0, 0, 0);
        ak[ftl][st] = __builtin_amdgcn_mfma_f32_16x16x32_bf16(xbh[st], kh, ak[ftl][st], 0, 0, 0);
        ak[ftl][st] = __builtin_amdgcn_mfma_f32_16x16x32_bf16(xbl[st], kh, ak[ftl][st], 0, 0, 0);
        ak[ftl][st] = __builtin_amdgcn_mfma_f32_16x16x32_bf16(xbh[st], kl, ak[ftl][st], 0, 0, 0);
      }
    }
  }

  ushort* Qnb = Qn + (size_t)b * NS * NE;
  ushort* Knb = Kn + (size_t)b * NS * NE;
  ushort* Vtb = Vt + (size_t)b * NE * NS;
  #pragma unroll
  for (int ftl = 0; ftl < 2; ++ftl) {
    const int f0 = (wv * 2 + ftl) * 16;
    #pragma unroll
    for (int r = 0; r < 4; ++r) {
      const int f = f0 + 4 * g + r;
      const float bvv = bv[f];
      #pragma unroll
      for (int st = 0; st < 4; ++st)
        Vtb[(size_t)f * NS + s0 + st * 16 + c] = f2bf(av[ftl][st][r] + bvv);
    }
    const float bqv = bq[f0 + c] * CSCALE;
    const float bkv = bk[f0 + c];
    #pragma unroll
    for (int st = 0; st < 4; ++st)
      #pragma unroll
      for (int r = 0; r < 4; ++r) {
        const size_t ro = (size_t)(s0 + st * 16 + 4 * g + r) * NE + f0 + c;
        Qnb[ro] = f2bf(aq[ftl][st][r] + bqv);
        Knb[ro] = f2bf(ak[ftl][st][r] + bkv);
      }
  }
}

// ------- flash attention: 4 waves = 2 strips x 2 k-slices, QW=64, KVB=32 ---
// 1 wave/SIMD (512-reg budget). Wave-private dbuf K/V tiles (proven R16
// layouts), barrier-free k-loop. Latency hidden by ILP: V register-pipelined
// one tile ahead (PV(t-1) has ZERO LDS dependency); all 16 ds_reads issued
// at tile top; both stages issued at top -> vmcnt(16) drains exactly
// K(t)+V(t), each a full tile old.
__global__ __launch_bounds__(256, 1) void attn_kernel(
    const ushort* __restrict__ Qn, const ushort* __restrict__ Kn,
    const ushort* __restrict__ Vt, float* __restrict__ out)
{
  const int tid = threadIdx.x;
  const int w = tid >> 6, lane = tid & 63;
  const int h = lane >> 5, q5 = lane & 31;
  const int strip = w >> 1;                    // q-strip (0/1)
  const int slice = w & 1;                     // k-slice (0/1), 2048 k each
  const int bid = blockIdx.x;
  const int b = bid & 7;                       // XCD pin: batch b -> XCD b
  const int qw = (bid >> 3) * 128 + strip * 64;

  const ushort* Qb = Qn + (size_t)b * NS * NE;
  const char*   Kb = (const char*)(Kn + (size_t)b * NS * NE);
  const char*   Vb = (const char*)(Vt + (size_t)b * NE * NS);

  __shared__ __align__(16) char lds[131072];   // 4 waves x [K dbuf 16K | V dbuf 16K]
  __shared__ float lx[2][2][2][32];            // [strip][slice][u][q5] lsum

  auto Kbuf = [&](int bf) -> char* { return lds + w * 32768 + bf * 8192; };
  auto Vbuf = [&](int bf) -> char* { return lds + w * 32768 + 16384 + bf * 8192; };

  // Q B-frags for both 32-q subtiles: lane holds Q[q][dc*16 + h*8 + j]
  s8v qfA[8], qfB[8];
  #pragma unroll
  for (int dc = 0; dc < 8; ++dc) {
    qfA[dc] = *(const s8v*)(Qb + (size_t)(qw + q5) * NE + dc * 16 + h * 8);
    qfB[dc] = *(const s8v*)(Qb + (size_t)(qw + 32 + q5) * NE + dc * 16 + h * 8);
  }

  // K tile [32 k][256B] xor16 (R16-proven); 8 gload_lds
  auto stageK = [&](int bf, int t) {
    const int kt = slice * 64 + t;
    const char* Ksrc = Kb + (size_t)kt * 8192;   // contiguous 8KB
    char* dst = Kbuf(bf);
    #pragma unroll
    for (int p = 0; p < 8; ++p) {
      const int off = p * 1024;
      const int lo = off + lane * 16;
      const int row = lo >> 8;
      gload_lds16(Ksrc + (lo ^ ((row & 15) << 4)), dst + off);
    }
  };
  // V quad-pack [32 rows][256B] xor16 (R16-proven): row r quarter j (64B)
  // holds d = r + 32j, k 0..31; 8 gload_lds
  auto stageV = [&](int bf, int t) {
    const int kt = slice * 64 + t;
    char* dst = Vbuf(bf);
    #pragma unroll
    for (int p = 0; p < 8; ++p) {
      const int off = p * 1024;
      const int lo = off + lane * 16;
      const int row = lo >> 8;
      const int inner = (lo & 255) ^ ((row & 15) << 4);
      const int d = row + 32 * (inner >> 6);
      gload_lds16(Vb + (size_t)d * (NS * 2) + kt * 64 + (inner & 63), dst + off);
    }
  };

  // fused exp2 -> bf16 PV B-frag (8 scores -> one frag, sums into l)
  auto expfrag8 = [&](float a0, float a1, float a2, float a3,
                      float a4, float a5, float a6, float a7, float& l) -> s8v {
    float p0 = __builtin_amdgcn_exp2f(a0), p1 = __builtin_amdgcn_exp2f(a1);
    float p2 = __builtin_amdgcn_exp2f(a2), p3 = __builtin_amdgcn_exp2f(a3);
    float p4 = __builtin_amdgcn_exp2f(a4), p5 = __builtin_amdgcn_exp2f(a5);
    float p6 = __builtin_amdgcn_exp2f(a6), p7 = __builtin_amdgcn_exp2f(a7);
    l += ((p0 + p1) + (p2 + p3)) + ((p4 + p5) + (p6 + p7));
    u32 A = cvtpk(p0, p1);
    u32 B = cvtpk(p4, p5);
    u32 C = cvtpk(p2, p3);
    u32 D = cvtpk(p6, p7);
    u2v rAB = __builtin_amdgcn_permlane32_swap(A, B, false, false);
    u2v rCD = __builtin_amdgcn_permlane32_swap(C, D, false, false);
    union { s8v v; u32 wd[4]; } P;
    P.wd[0] = rAB[0]; P.wd[1] = rCD[0]; P.wd[2] = rAB[1]; P.wd[3] = rCD[1];
    return P.v;
  };

  f16v oA[4], oB[4];
  #pragma unroll
  for (int dt = 0; dt < 4; ++dt) {
    oA[dt] = (f16v){0,0,0,0,0,0,0,0,0,0,0,0,0,0,0,0};
    oB[dt] = (f16v){0,0,0,0,0,0,0,0,0,0,0,0,0,0,0,0};
  }
  float lA = 0.f, lB = 0.f;
  s8v PA0 = (s8v){0,0,0,0,0,0,0,0}, PA1 = PA0, PB0 = PA0, PB1 = PA0;
  s8v vfA[8], vfB[8];
  #pragma unroll
  for (int i = 0; i < 8; ++i) { vfA[i] = PA0; vfB[i] = PA0; }

  // tile body: PV(t-1) from vfp regs (read at top of t-1); reads vfn <- V(t)
  auto body = [&](int t, s8v (&vfp)[8], s8v (&vfn)[8], bool dopv) {
    const int tn = (t + 1 < 64) ? t + 1 : 63;   // uniform re-issue on last
    stageK((t + 1) & 1, tn);                    // +8
    stageV((t + 1) & 1, tn);                    // +8
    // in-flight = 32; drain to 16 -> K(t),V(t) resident (issued a tile ago)
    asm volatile("s_waitcnt vmcnt(16)" ::: "memory");
    __builtin_amdgcn_sched_barrier(0);

    const char* bK = Kbuf(t & 1);
    const char* bV = Vbuf(t & 1);
    // ---- issue all 16 ds_reads back-to-back
    s8v kf[8];
    #pragma unroll
    for (int dc = 0; dc < 8; ++dc)
      kf[dc] = *(const s8v*)(bK + q5 * 256 + ((dc * 32 + h * 16) ^ ((q5 & 15) << 4)));
    #pragma unroll
    for (int dt = 0; dt < 4; ++dt) {
      vfn[2*dt]   = *(const s8v*)(bV + q5 * 256 + ((dt * 64 + h * 16)      ^ ((q5 & 15) << 4)));
      vfn[2*dt+1] = *(const s8v*)(bV + q5 * 256 + ((dt * 64 + 32 + h * 16) ^ ((q5 & 15) << 4)));
    }
    // ---- QK(t): S^T[k][q] for both q-subtiles (K frag shared)
    f16v sA = (f16v){0,0,0,0,0,0,0,0,0,0,0,0,0,0,0,0};
    f16v sB = (f16v){0,0,0,0,0,0,0,0,0,0,0,0,0,0,0,0};
    __builtin_amdgcn_s_setprio(1);
    #pragma unroll
    for (int dc = 0; dc < 8; ++dc) {
      sA = __builtin_amdgcn_mfma_f32_32x32x16_bf16(kf[dc], qfA[dc], sA, 0, 0, 0);
      sB = __builtin_amdgcn_mfma_f32_32x32x16_bf16(kf[dc], qfB[dc], sB, 0, 0, 0);
    }
    __builtin_amdgcn_s_setprio(0);
    // ---- PV(t-1): pure-register MFMA stream, zero LDS dependency
    if (dopv) {
      __builtin_amdgcn_s_setprio(1);
      #pragma unroll
      for (int dt = 0; dt < 4; ++dt) {
        oA[dt] = __builtin_amdgcn_mfma_f32_32x32x16_bf16(vfp[2*dt],   PA0, oA[dt], 0, 0, 0);
        oB[dt] = __builtin_amdgcn_mfma_f32_32x32x16_bf16(vfp[2*dt],   PB0, oB[dt], 0, 0, 0);
        oA[dt] = __builtin_amdgcn_mfma_f32_32x32x16_bf16(vfp[2*dt+1], PA1, oA[dt], 0, 0, 0);
        oB[dt] = __builtin_amdgcn_mfma_f32_32x32x16_bf16(vfp[2*dt+1], PB1, oB[dt], 0, 0, 0);
      }
      __builtin_amdgcn_s_setprio(0);
    }
    // ---- SM(t): scores -> P frags for next tile's PV
    PA0 = expfrag8(sA[0], sA[1], sA[2], sA[3], sA[4], sA[5], sA[6], sA[7], lA);
    PA1 = expfrag8(sA[8], sA[9], sA[10], sA[11], sA[12], sA[13], sA[14], sA[15], lA);
    PB0 = expfrag8(sB[0], sB[1], sB[2], sB[3], sB[4], sB[5], sB[6], sB[7], lB);
    PB1 = expfrag8(sB[8], sB[9], sB[10], sB[11], sB[12], sB[13], sB[14], sB[15], lB);
  };

  stageK(0, 0);
  stageV(0, 0);

  #pragma unroll 1
  for (int t = 0; t < 64; t += 2) {
    body(t,     vfB, vfA, t > 0);   // PV(t-1) uses vfB (read at t-1); reads vfA <- V(t)
    body(t + 1, vfA, vfB, true);    // PV(t) uses vfA; reads vfB <- V(t+1)
  }
  // epilogue PV(63): vfB holds V(63) (read in body 63); P from SM(63)
  __builtin_amdgcn_s_setprio(1);
  #pragma unroll
  for (int dt = 0; dt < 4; ++dt) {
    oA[dt] = __builtin_amdgcn_mfma_f32_32x32x16_bf16(vfB[2*dt],   PA0, oA[dt], 0, 0, 0);
    oB[dt] = __builtin_amdgcn_mfma_f32_32x32x16_bf16(vfB[2*dt],   PB0, oB[dt], 0, 0, 0);
    oA[dt] = __builtin_amdgcn_mfma_f32_32x32x16_bf16(vfB[2*dt+1], PA1, oA[dt], 0, 0, 0);
    oB[dt] = __builtin_amdgcn_mfma_f32_32x32x16_bf16(vfB[2*dt+1], PB1, oB[dt], 0, 0, 0);
  }
  __builtin_amdgcn_s_setprio(0);

  // ---- 2-slice combine per strip via (dead) LDS ---------------------------
  lA += __shfl_xor(lA, 32);
  lB += __shfl_xor(lB, 32);
  if (h == 0) { lx[strip][slice][0][q5] = lA; lx[strip][slice][1][q5] = lB; }
  float* cb = (float*)lds;                 // [strip][128 e][64 q] f32 = 64 KB
  const int base = strip * 8192;
  __syncthreads();                         // drains stray re-issued loads too
  if (slice == 1) {
    #pragma unroll
    for (int dt = 0; dt < 4; ++dt)
      #pragma unroll
      for (int r = 0; r < 16; ++r) {
        const int e = dt * 32 + (r & 3) + 8 * (r >> 2) + 4 * h;
        cb[base + e * 64 + q5]      = oA[dt][r];
        cb[base + e * 64 + 32 + q5] = oB[dt][r];
      }
  }
  __syncthreads();
  if (slice == 0) {
    const float rA = 1.0f / (lx[strip][0][0][q5] + lx[strip][1][0][q5]);
    const float rB = 1.0f / (lx[strip][0][1][q5] + lx[strip][1][1][q5]);
    float* ob = out + (size_t)b * NE * NS;
    #pragma unroll
    for (int dt = 0; dt < 4; ++dt)
      #pragma unroll
      for (int r = 0; r < 16; ++r) {
        const int e = dt * 32 + (r & 3) + 8 * (r >> 2) + 4 * h;
        ob[(size_t)e * NS + qw + q5] =
            (oA[dt][r] + cb[base + e * 64 + q5]) * rA;
        ob[(size_t)e * NS + qw + 32 + q5] =
            (oB[dt][r] + cb[base + e * 64 + 32 + q5]) * rB;
      }
  }
}

extern "C" void kernel_launch(void* const* d_in, const int* in_sizes, int n_in,
                              void* d_out, int out_size, void* d_ws, size_t ws_size,
                              hipStream_t stream) {
  (void)in_sizes; (void)n_in; (void)out_size; (void)ws_size;
  const float* x  = (const float*)d_in[0];
  const float* Wq = (const float*)d_in[1];
  const float* bq = (const float*)d_in[2];
  const float* Wk = (const float*)d_in[3];
  const float* bk = (const float*)d_in[4];
  const float* Wv = (const float*)d_in[5];
  const float* bv = (const float*)d_in[6];
  float* out = (float*)d_out;

  ushort* Qn = (ushort*)d_ws;                      // [B][S][D] bf16, 8 MB
  ushort* Kn = Qn + (size_t)NB * NS * NE;          // [B][S][D] bf16, 8 MB
  ushort* Vt = Kn + (size_t)NB * NS * NE;          // [B][D][S] bf16, 8 MB

  proj_gemm<<<dim3(NS / 64 * NB), 256, 0, stream>>>(x, Wq, bq, Wk, bk, Wv, bv, Qn, Kn, Vt);
  attn_kernel<<<dim3(NS / 128 * NB), 256, 0, stream>>>(Qn, Kn, Vt, out);
}